// Round 6
// baseline (250.155 us; speedup 1.0000x reference)
//
#include <hip/hip_runtime.h>

// ---------- types ----------
typedef __bf16 bf16x8 __attribute__((ext_vector_type(8)));
typedef float  f32x4  __attribute__((ext_vector_type(4)));

__device__ __forceinline__ unsigned short f2bf(float f) {
    union { float f; unsigned int u; } x; x.f = f;
    unsigned int r = (x.u + 0x7FFFu + ((x.u >> 16) & 1u)) >> 16;  // RNE
    return (unsigned short)r;
}
__device__ __forceinline__ float bf2f(unsigned int hi) {
    union { unsigned int u; float f; } x; x.u = hi; return x.f;
}

// async global->LDS, 16B per lane; LDS dst is wave-uniform base + lane*16
typedef const __attribute__((address_space(1))) unsigned short gu16;
typedef __attribute__((address_space(3)))       unsigned short lu16;
__device__ __forceinline__ void gl_lds16(const unsigned short* g, unsigned short* l) {
    __builtin_amdgcn_global_load_lds((gu16*)g, (lu16*)l, 16, 0, 0);
}

// ==========================================================================
// GEMM core, templated on MF (A-frags per wave in M).
// Block tile (MF*32) x 128, BK=32, 256 thr = 4 waves (2x2).
// Wave tile (MF*16) x 64: MF x 4 MFMA 16x16x32, acc MF*4 f32x4.
// MF=4: 128x128 (R4-proven). MF=8: 256x128, 384 B LDS-read/MFMA (vs 512).
// A [m][k] k-contig (lda), B [n][k] k-contig (ldb). K % 32 == 0.
// ==========================================================================
template<int MF>
__device__ __forceinline__ void gemm_core(
    const unsigned short* __restrict__ Ab, int lda,
    const unsigned short* __restrict__ Bb, int ldb,
    int K, f32x4 (&acc)[MF][4],
    unsigned short* As, unsigned short* Bs)
{
    const int tid  = threadIdx.x;
    const int lane = tid & 63;
    const int wave = tid >> 6;
    const int wm   = (wave >> 1) * (MF * 16);
    const int wn   = (wave & 1) * 64;
    const int l16  = lane & 15;
    const int quad = lane >> 4;

    // staging map per 64-row chunk: wave w writes rows [ch*64+w*16, +16)
    const int r0 = wave * 16 + (lane >> 2);
    const int c0 = (lane & 3) * 8;

    for (int k0 = 0; k0 < K; k0 += 32) {
        __syncthreads();
        #pragma unroll
        for (int ch = 0; ch < MF / 2; ch++)
            gl_lds16(Ab + (long)(r0 + ch * 64) * lda + c0 + k0,
                     As + ch * 2048 + wave * 512);
        #pragma unroll
        for (int ch = 0; ch < 2; ch++)
            gl_lds16(Bb + (long)(r0 + ch * 64) * ldb + c0 + k0,
                     Bs + ch * 2048 + wave * 512);
        __syncthreads();

        bf16x8 af[MF], bfr[4];
        #pragma unroll
        for (int mi = 0; mi < MF; mi++)
            af[mi] = *(const bf16x8*)&As[(wm + mi * 16 + l16) * 32 + quad * 8];
        #pragma unroll
        for (int ni = 0; ni < 4; ni++)
            bfr[ni] = *(const bf16x8*)&Bs[(wn + ni * 16 + l16) * 32 + quad * 8];
        #pragma unroll
        for (int mi = 0; mi < MF; mi++)
            #pragma unroll
            for (int ni = 0; ni < 4; ni++)
                acc[mi][ni] = __builtin_amdgcn_mfma_f32_16x16x32_bf16(af[mi], bfr[ni], acc[mi][ni], 0, 0, 0);
    }
}

// ==========================================================================
// Generic GEMM kernel: optional trans-out / bias / residual
// ==========================================================================
template<int MF, typename OutT, bool TRANS_OUT, bool HAS_BIAS, bool HAS_RESID>
__global__ __launch_bounds__(256, 2) void gemm_k(
    const unsigned short* __restrict__ Ag, long sA, int lda,
    const unsigned short* __restrict__ Bg, long sB, int ldb,
    OutT* __restrict__ Cg, long sC, int ldc,
    const float* __restrict__ bias,
    const float* __restrict__ resid, long sR,
    float alpha, int K)
{
    __shared__ __align__(16) unsigned short As[MF * 1024];  // (MF*32) x 32
    __shared__ __align__(16) unsigned short Bs[128 * 32];

    const unsigned short* Ab = Ag + (long)blockIdx.z * sA + (long)(blockIdx.y * MF * 32) * lda;
    const unsigned short* Bb = Bg + (long)blockIdx.z * sB + (long)(blockIdx.x * 128) * ldb;

    f32x4 acc[MF][4] = {};
    gemm_core<MF>(Ab, lda, Bb, ldb, K, acc, As, Bs);

    const int lane = threadIdx.x & 63;
    const int wave = threadIdx.x >> 6;
    const int l16  = lane & 15;
    const int quad = lane >> 4;
    const int mb = blockIdx.y * MF * 32 + (wave >> 1) * MF * 16;
    const int nb = blockIdx.x * 128 + (wave & 1) * 64;

    #pragma unroll
    for (int mi = 0; mi < MF; mi++) {
        #pragma unroll
        for (int ni = 0; ni < 4; ni++) {
            f32x4 v = acc[mi][ni];
            const int m0 = mb + mi * 16 + quad * 4;
            const int n  = nb + ni * 16 + l16;
            float o[4];
            #pragma unroll
            for (int r = 0; r < 4; r++) {
                float val = v[r] * alpha;
                if (HAS_BIAS) val += bias[m0 + r];
                o[r] = val;
            }
            if constexpr (!TRANS_OUT) {
                const long base = (long)blockIdx.z * sC;
                #pragma unroll
                for (int r = 0; r < 4; r++) {
                    float val = o[r];
                    if (HAS_RESID) val += resid[(long)blockIdx.z * sR + (long)(m0 + r) * ldc + n];
                    long idx = base + (long)(m0 + r) * ldc + n;
                    if constexpr (sizeof(OutT) == 2) ((unsigned short*)Cg)[idx] = f2bf(val);
                    else                              ((float*)Cg)[idx] = val;
                }
            } else {
                const long idx = (long)blockIdx.z * sC + (long)n * ldc + m0;
                if constexpr (sizeof(OutT) == 2) {
                    ushort4 p; p.x = f2bf(o[0]); p.y = f2bf(o[1]); p.z = f2bf(o[2]); p.w = f2bf(o[3]);
                    *(ushort4*)((unsigned short*)Cg + idx) = p;
                } else {
                    float4 p; p.x = o[0]; p.y = o[1]; p.z = o[2]; p.w = o[3];
                    *(float4*)((float*)Cg + idx) = p;
                }
            }
        }
    }
}

// ==========================================================================
// Fused QKV GEMM (MF=8): A = Wqkv [1536][512] (wq|wk|wv), B = xnT [n][c].
// 256-row tiles: blockIdx.y 0-1 -> qT (trans), 2-3 -> kT (trans),
// 4-5 -> vB[c][j] (natural). Grid (8, 6, 16) = 768 blocks.
// ==========================================================================
__global__ __launch_bounds__(256, 2) void qkv_k(
    const unsigned short* __restrict__ Wqkv,
    const unsigned short* __restrict__ xnT,
    unsigned short* __restrict__ qT,
    unsigned short* __restrict__ kT,
    unsigned short* __restrict__ vB,
    const float* __restrict__ bqkv)
{
    constexpr int MF = 8;
    __shared__ __align__(16) unsigned short As[MF * 1024];
    __shared__ __align__(16) unsigned short Bs[128 * 32];

    const unsigned short* Ab = Wqkv + (long)(blockIdx.y * 256) * 512;
    const unsigned short* Bb = xnT + (long)blockIdx.z * 524288 + (long)(blockIdx.x * 128) * 512;

    f32x4 acc[MF][4] = {};
    gemm_core<MF>(Ab, 512, Bb, 512, 512, acc, As, Bs);

    const int lane = threadIdx.x & 63;
    const int wave = threadIdx.x >> 6;
    const int l16  = lane & 15;
    const int quad = lane >> 4;
    const int mb = blockIdx.y * 256 + (wave >> 1) * 128;  // global row in [0,1536)
    const int nb = blockIdx.x * 128 + (wave & 1) * 64;

    const int mat = blockIdx.y >> 1;                      // 0=q 1=k 2=v (block-uniform)
    const long zb = (long)blockIdx.z * 524288;

    #pragma unroll
    for (int mi = 0; mi < MF; mi++) {
        #pragma unroll
        for (int ni = 0; ni < 4; ni++) {
            f32x4 v = acc[mi][ni];
            const int m0 = mb + mi * 16 + quad * 4;       // global row
            const int n  = nb + ni * 16 + l16;
            float o[4];
            #pragma unroll
            for (int r = 0; r < 4; r++) o[r] = v[r] + bqkv[m0 + r];
            const int ml = m0 & 511;                      // row within matrix
            if (mat == 2) {
                #pragma unroll
                for (int r = 0; r < 4; r++)
                    vB[zb + (long)(ml + r) * 1024 + n] = f2bf(o[r]);
            } else {
                unsigned short* dst = (mat == 0) ? qT : kT;
                ushort4 p; p.x = f2bf(o[0]); p.y = f2bf(o[1]); p.z = f2bf(o[2]); p.w = f2bf(o[3]);
                *(ushort4*)(dst + zb + (long)n * 512 + ml) = p;
            }
        }
    }
}

// ==========================================================================
// Softmax: one WAVE per row (no barriers, no LDS). 4 rows/block.
// S bf16 [16][1024][1024] in place. 16 elems/lane = 2x uint4.
// ==========================================================================
__global__ __launch_bounds__(256) void softmax_k(unsigned short* __restrict__ S)
{
    const int wv   = threadIdx.x >> 6;
    const int lane = threadIdx.x & 63;
    const long row = (long)blockIdx.y * 1024 + blockIdx.x * 4 + wv;
    unsigned short* sp = S + row * 1024;

    uint4 u0 = ((const uint4*)sp)[lane];
    uint4 u1 = ((const uint4*)sp)[lane + 64];

    float f[16];
    const unsigned int* up = (const unsigned int*)&u0;
    #pragma unroll
    for (int i = 0; i < 4; i++) {
        f[2 * i]     = bf2f(up[i] << 16);
        f[2 * i + 1] = bf2f(up[i] & 0xFFFF0000u);
    }
    up = (const unsigned int*)&u1;
    #pragma unroll
    for (int i = 0; i < 4; i++) {
        f[8 + 2 * i] = bf2f(up[i] << 16);
        f[9 + 2 * i] = bf2f(up[i] & 0xFFFF0000u);
    }

    float mx = f[0];
    #pragma unroll
    for (int i = 1; i < 16; i++) mx = fmaxf(mx, f[i]);
    #pragma unroll
    for (int o = 1; o < 64; o <<= 1) mx = fmaxf(mx, __shfl_xor(mx, o));

    float sum = 0.f;
    #pragma unroll
    for (int i = 0; i < 16; i++) { f[i] = __expf(f[i] - mx); sum += f[i]; }
    #pragma unroll
    for (int o = 1; o < 64; o <<= 1) sum += __shfl_xor(sum, o);
    const float inv = 1.f / sum;

    uint4 w0, w1;
    unsigned int* wp = (unsigned int*)&w0;
    #pragma unroll
    for (int i = 0; i < 4; i++)
        wp[i] = (unsigned int)f2bf(f[2 * i] * inv) | ((unsigned int)f2bf(f[2 * i + 1] * inv) << 16);
    wp = (unsigned int*)&w1;
    #pragma unroll
    for (int i = 0; i < 4; i++)
        wp[i] = (unsigned int)f2bf(f[8 + 2 * i] * inv) | ((unsigned int)f2bf(f[9 + 2 * i] * inv) << 16);

    ((uint4*)sp)[lane]      = w0;
    ((uint4*)sp)[lane + 64] = w1;
}

// ==========================================================================
// GroupNorm: x[b][c][n] (fp32) -> xnT[b][n][c] (bf16), 32 groups of 16 ch
// ==========================================================================
__global__ __launch_bounds__(256) void gn_k(
    const float* __restrict__ x, const float* __restrict__ gsc,
    const float* __restrict__ gbi, unsigned short* __restrict__ xnT)
{
    __shared__ __align__(16) unsigned short ln[16 * 1024];
    __shared__ float red[8];
    const int b = blockIdx.y, g = blockIdx.x;
    const int tid = threadIdx.x, lane = tid & 63, wv = tid >> 6;

    const float4* x4 = (const float4*)(x + ((long)b * 512 + g * 16) * 1024);
    float4 vals[16];
    float s = 0.f, ss = 0.f;
    #pragma unroll
    for (int i = 0; i < 16; i++) {
        float4 v = x4[tid + i * 256];
        vals[i] = v;
        s  += v.x + v.y + v.z + v.w;
        ss += v.x * v.x + v.y * v.y + v.z * v.z + v.w * v.w;
    }
    for (int o = 32; o; o >>= 1) { s += __shfl_down(s, o); ss += __shfl_down(ss, o); }
    if (lane == 0) { red[wv * 2] = s; red[wv * 2 + 1] = ss; }
    __syncthreads();
    const float S  = red[0] + red[2] + red[4] + red[6];
    const float SS = red[1] + red[3] + red[5] + red[7];
    const float mean = S * (1.f / 16384.f);
    const float var  = SS * (1.f / 16384.f) - mean * mean;
    const float inv  = rsqrtf(var + 1e-5f);

    #pragma unroll
    for (int i = 0; i < 16; i++) {
        const int idx = tid + i * 256;
        const int c   = idx >> 8;
        const float sc = gsc[g * 16 + c] * inv;
        const float bi = gbi[g * 16 + c] - mean * sc;
        float4 v = vals[i];
        ushort4 p;
        p.x = f2bf(v.x * sc + bi); p.y = f2bf(v.y * sc + bi);
        p.z = f2bf(v.z * sc + bi); p.w = f2bf(v.w * sc + bi);
        ((ushort4*)ln)[idx] = p;
    }
    __syncthreads();

    unsigned short* op = xnT + (long)b * 1024 * 512 + g * 16;
    for (int rep = 0; rep < 4; rep++) {
        const int n = rep * 256 + tid;
        union { unsigned short u[16]; uint4 v[2]; } t;
        #pragma unroll
        for (int c = 0; c < 16; c++) t.u[c] = ln[c * 1024 + n];
        *(uint4*)&op[(long)n * 512]     = t.v[0];
        *(uint4*)&op[(long)n * 512 + 8] = t.v[1];
    }
}

// ---------- weights fp32 -> bf16 + bias concat (y==4 path) ----------
__global__ __launch_bounds__(256) void wconv_k(
    const float* __restrict__ w0, const float* __restrict__ w1,
    const float* __restrict__ w2, const float* __restrict__ w3,
    const float* __restrict__ b0, const float* __restrict__ b1,
    const float* __restrict__ b2,
    unsigned short* __restrict__ out, float* __restrict__ bqkv)
{
    const int m = blockIdx.y;
    const int i = blockIdx.x * 256 + threadIdx.x;
    if (m == 4) {
        if (i < 384) {
            const int which = i >> 7, off = i & 127;
            const float* src = (which == 0) ? b0 : (which == 1) ? b1 : b2;
            ((float4*)bqkv)[i] = ((const float4*)src)[off];
        }
        return;
    }
    const float* src = (m == 0) ? w0 : (m == 1) ? w1 : (m == 2) ? w2 : w3;
    float4 v = ((const float4*)src)[i];
    ushort4 o; o.x = f2bf(v.x); o.y = f2bf(v.y); o.z = f2bf(v.z); o.w = f2bf(v.w);
    ((ushort4*)(out + (long)m * 262144))[i] = o;
}

// ==========================================================================
extern "C" void kernel_launch(void* const* d_in, const int* in_sizes, int n_in,
                              void* d_out, int out_size, void* d_ws, size_t ws_size,
                              hipStream_t stream)
{
    const float* x   = (const float*)d_in[0];
    const float* gsc = (const float*)d_in[1];
    const float* gbi = (const float*)d_in[2];
    const float* wq  = (const float*)d_in[3];
    const float* bq  = (const float*)d_in[4];
    const float* wk  = (const float*)d_in[5];
    const float* bk  = (const float*)d_in[6];
    const float* wv  = (const float*)d_in[7];
    const float* bv  = (const float*)d_in[8];
    const float* wp  = (const float*)d_in[9];
    const float* bp  = (const float*)d_in[10];
    float* out = (float*)d_out;

    char* ws = (char*)d_ws;
    unsigned short* xnT = (unsigned short*)(ws);               // 16 MB [b][n][c]; reused as OT
    unsigned short* qT  = (unsigned short*)(ws + 16777216);    // 16 MB [b][i][c]
    unsigned short* kT  = (unsigned short*)(ws + 33554432);    // 16 MB [b][j][c]
    unsigned short* vB  = (unsigned short*)(ws + 50331648);    // 16 MB [b][c][j]
    unsigned short* Sb  = (unsigned short*)(ws + 67108864);    // 32 MB [b][i][j] bf16
    unsigned short* Wb  = (unsigned short*)(ws + 100663296);   // 2 MB: wq|wk|wv|wp bf16
    float*          bqkv= (float*)        (ws + 102760448);    // 6 KB
    unsigned short* OT  = xnT;

    const long sBCN = 512L * 1024;

    wconv_k<<<dim3(256, 5), 256, 0, stream>>>(wq, wk, wv, wp, bq, bk, bv, Wb, bqkv);
    gn_k<<<dim3(32, 16), 256, 0, stream>>>(x, gsc, gbi, xnT);

    // fused QKV (MF=8, 256x128 tiles): qT[i][c], kT[j][c], vB[c][j]
    qkv_k<<<dim3(8, 6, 16), 256, 0, stream>>>(Wb, xnT, qT, kT, vB, bqkv);

    // S[i][j] = (1/sqrt(512)) * q·k -> bf16   (MF=8: 256x128 tiles)
    gemm_k<8, unsigned short, false, false, false><<<dim3(8, 4, 16), 256, 0, stream>>>(
        qT, sBCN, 512, kT, sBCN, 512, Sb, 1048576L, 1024, nullptr, nullptr, 0,
        0.044194173824159216f, 512);
    softmax_k<<<dim3(256, 16), 256, 0, stream>>>(Sb);
    // O[c][i] = sum_j v[c][j]*A[i][j] -> OT[i][c]   (MF=4)
    gemm_k<4, unsigned short, true, false, false><<<dim3(8, 4, 16), 256, 0, stream>>>(
        vB, sBCN, 1024, Sb, 1048576L, 1024, OT, sBCN, 512,
        nullptr, nullptr, 0, 1.f, 1024);
    // out = Wp * O + bp + x   (MF=4)
    gemm_k<4, float, false, true, true><<<dim3(8, 4, 16), 256, 0, stream>>>(
        Wb + 786432, 0, 512, OT, sBCN, 512, out, sBCN, 1024, bp, x, sBCN, 1.f, 512);
}

// Round 7
// 238.934 us; speedup vs baseline: 1.0470x; 1.0470x over previous
//
#include <hip/hip_runtime.h>

// ---------- types ----------
typedef __bf16 bf16x8 __attribute__((ext_vector_type(8)));
typedef float  f32x4  __attribute__((ext_vector_type(4)));

__device__ __forceinline__ unsigned short f2bf(float f) {
    union { float f; unsigned int u; } x; x.f = f;
    unsigned int r = (x.u + 0x7FFFu + ((x.u >> 16) & 1u)) >> 16;  // RNE
    return (unsigned short)r;
}
__device__ __forceinline__ float bf2f(unsigned int hi) {
    union { unsigned int u; float f; } x; x.u = hi; return x.f;
}

// async global->LDS, 16B per lane; LDS dst is wave-uniform base + lane*16
typedef const __attribute__((address_space(1))) unsigned short gu16;
typedef __attribute__((address_space(3)))       unsigned short lu16;
__device__ __forceinline__ void gl_lds16(const unsigned short* g, unsigned short* l) {
    __builtin_amdgcn_global_load_lds((gu16*)g, (lu16*)l, 16, 0, 0);
}

// ==========================================================================
// Double-buffered GEMM core (MF=4): 128x128 tile, BK=32, 4 waves (2x2),
// wave 64x64. Prefetch for iter k+1 issues right after the barrier of iter
// k, so the vmcnt(0)-at-barrier drain lands a full compute phase after
// issue. LDS: As/Bs = 2 buffers x 8 KB each (32 KB total).
// A [m][k] k-contig (lda), B [n][k] k-contig (ldb). K % 32 == 0.
// ==========================================================================
__device__ __forceinline__ void stage_tiles(
    const unsigned short* __restrict__ Ab, int lda,
    const unsigned short* __restrict__ Bb, int ldb,
    int k0, unsigned short* Ad, unsigned short* Bd,
    int wave, int r0, int c0)
{
    gl_lds16(Ab + (long)r0 * lda + c0 + k0,        Ad + wave * 512);
    gl_lds16(Ab + (long)(r0 + 64) * lda + c0 + k0, Ad + 2048 + wave * 512);
    gl_lds16(Bb + (long)r0 * ldb + c0 + k0,        Bd + wave * 512);
    gl_lds16(Bb + (long)(r0 + 64) * ldb + c0 + k0, Bd + 2048 + wave * 512);
}

__device__ __forceinline__ void gemm_core_db(
    const unsigned short* __restrict__ Ab, int lda,
    const unsigned short* __restrict__ Bb, int ldb,
    int K, f32x4 (&acc)[4][4],
    unsigned short* As, unsigned short* Bs)   // As[2*4096], Bs[2*4096]
{
    const int tid  = threadIdx.x;
    const int lane = tid & 63;
    const int wave = tid >> 6;
    const int wm   = (wave >> 1) * 64;
    const int wn   = (wave & 1) * 64;
    const int l16  = lane & 15;
    const int quad = lane >> 4;

    const int r0 = wave * 16 + (lane >> 2);
    const int c0 = (lane & 3) * 8;

    stage_tiles(Ab, lda, Bb, ldb, 0, As, Bs, wave, r0, c0);

    int sel = 0;
    for (int k0 = 0; k0 < K; k0 += 32) {
        __syncthreads();   // buf[sel] arrived (own vmcnt drained; all waves past reads of buf[sel^1])
        if (k0 + 32 < K)
            stage_tiles(Ab, lda, Bb, ldb, k0 + 32,
                        As + (sel ^ 1) * 4096, Bs + (sel ^ 1) * 4096, wave, r0, c0);

        const unsigned short* Ap = As + sel * 4096;
        const unsigned short* Bp = Bs + sel * 4096;
        bf16x8 af[4], bfr[4];
        #pragma unroll
        for (int mi = 0; mi < 4; mi++)
            af[mi] = *(const bf16x8*)&Ap[(wm + mi * 16 + l16) * 32 + quad * 8];
        #pragma unroll
        for (int ni = 0; ni < 4; ni++)
            bfr[ni] = *(const bf16x8*)&Bp[(wn + ni * 16 + l16) * 32 + quad * 8];
        #pragma unroll
        for (int mi = 0; mi < 4; mi++)
            #pragma unroll
            for (int ni = 0; ni < 4; ni++)
                acc[mi][ni] = __builtin_amdgcn_mfma_f32_16x16x32_bf16(af[mi], bfr[ni], acc[mi][ni], 0, 0, 0);
        sel ^= 1;
    }
}

// ==========================================================================
// Generic GEMM kernel. EXP_SUM (natural only): C = exp(alpha*acc) bf16 and
// atomicAdd per-row sums into lsum. ROW_SCALE (trans only): scale by
// 1/lsum[n] before store.
// ==========================================================================
template<typename OutT, bool TRANS_OUT, bool HAS_BIAS, bool HAS_RESID,
         bool EXP_SUM, bool ROW_SCALE>
__global__ __launch_bounds__(256) void gemm_k(
    const unsigned short* __restrict__ Ag, long sA, int lda,
    const unsigned short* __restrict__ Bg, long sB, int ldb,
    OutT* __restrict__ Cg, long sC, int ldc,
    const float* __restrict__ bias,
    const float* __restrict__ resid, long sR,
    float* __restrict__ lsum, long sL,
    float alpha, int K)
{
    __shared__ __align__(16) unsigned short As[2 * 4096];
    __shared__ __align__(16) unsigned short Bs[2 * 4096];

    const unsigned short* Ab = Ag + (long)blockIdx.z * sA + (long)(blockIdx.y * 128) * lda;
    const unsigned short* Bb = Bg + (long)blockIdx.z * sB + (long)(blockIdx.x * 128) * ldb;

    f32x4 acc[4][4] = {};
    gemm_core_db(Ab, lda, Bb, ldb, K, acc, As, Bs);

    const int lane = threadIdx.x & 63;
    const int wave = threadIdx.x >> 6;
    const int l16  = lane & 15;
    const int quad = lane >> 4;
    const int mb = blockIdx.y * 128 + (wave >> 1) * 64;
    const int nb = blockIdx.x * 128 + (wave & 1) * 64;

    #pragma unroll
    for (int mi = 0; mi < 4; mi++) {
        float rsum[4];
        if constexpr (EXP_SUM) { rsum[0] = rsum[1] = rsum[2] = rsum[3] = 0.f; }
        #pragma unroll
        for (int ni = 0; ni < 4; ni++) {
            f32x4 v = acc[mi][ni];
            const int m0 = mb + mi * 16 + quad * 4;
            const int n  = nb + ni * 16 + l16;
            float o[4];
            float invl;
            if constexpr (ROW_SCALE) invl = 1.f / lsum[(long)blockIdx.z * sL + n];
            #pragma unroll
            for (int r = 0; r < 4; r++) {
                float val = v[r] * alpha;
                if (HAS_BIAS) val += bias[m0 + r];
                if constexpr (EXP_SUM) { val = __expf(val); rsum[r] += val; }
                if constexpr (ROW_SCALE) val *= invl;
                o[r] = val;
            }
            if constexpr (!TRANS_OUT) {
                const long base = (long)blockIdx.z * sC;
                #pragma unroll
                for (int r = 0; r < 4; r++) {
                    float val = o[r];
                    if (HAS_RESID) val += resid[(long)blockIdx.z * sR + (long)(m0 + r) * ldc + n];
                    long idx = base + (long)(m0 + r) * ldc + n;
                    if constexpr (sizeof(OutT) == 2) ((unsigned short*)Cg)[idx] = f2bf(val);
                    else                              ((float*)Cg)[idx] = val;
                }
            } else {
                const long idx = (long)blockIdx.z * sC + (long)n * ldc + m0;
                if constexpr (sizeof(OutT) == 2) {
                    ushort4 p; p.x = f2bf(o[0]); p.y = f2bf(o[1]); p.z = f2bf(o[2]); p.w = f2bf(o[3]);
                    *(ushort4*)((unsigned short*)Cg + idx) = p;
                } else {
                    float4 p; p.x = o[0]; p.y = o[1]; p.z = o[2]; p.w = o[3];
                    *(float4*)((float*)Cg + idx) = p;
                }
            }
        }
        if constexpr (EXP_SUM) {
            const int m0 = mb + mi * 16 + quad * 4;
            #pragma unroll
            for (int r = 0; r < 4; r++) {
                float s = rsum[r];
                s += __shfl_xor(s, 1); s += __shfl_xor(s, 2);
                s += __shfl_xor(s, 4); s += __shfl_xor(s, 8);
                if (l16 == 0)
                    atomicAdd(&lsum[(long)blockIdx.z * sL + m0 + r], s);
            }
        }
    }
}

// ==========================================================================
// Fused QKV GEMM: A = Wqkv [1536][512] (wq|wk|wv), B = xnT [n][c].
// blockIdx.y 0..3 -> qT (trans), 4..7 -> kT (trans), 8..11 -> vB (natural).
// Grid (8, 12, 16) = 1536 blocks.
// ==========================================================================
__global__ __launch_bounds__(256) void qkv_k(
    const unsigned short* __restrict__ Wqkv,
    const unsigned short* __restrict__ xnT,
    unsigned short* __restrict__ qT,
    unsigned short* __restrict__ kT,
    unsigned short* __restrict__ vB,
    const float* __restrict__ bqkv)
{
    __shared__ __align__(16) unsigned short As[2 * 4096];
    __shared__ __align__(16) unsigned short Bs[2 * 4096];

    const unsigned short* Ab = Wqkv + (long)(blockIdx.y * 128) * 512;
    const unsigned short* Bb = xnT + (long)blockIdx.z * 524288 + (long)(blockIdx.x * 128) * 512;

    f32x4 acc[4][4] = {};
    gemm_core_db(Ab, 512, Bb, 512, 512, acc, As, Bs);

    const int lane = threadIdx.x & 63;
    const int wave = threadIdx.x >> 6;
    const int l16  = lane & 15;
    const int quad = lane >> 4;
    const int mb = blockIdx.y * 128 + (wave >> 1) * 64;   // global row in [0,1536)
    const int nb = blockIdx.x * 128 + (wave & 1) * 64;

    const int mat = blockIdx.y >> 2;                      // 0=q 1=k 2=v (block-uniform)
    const long zb = (long)blockIdx.z * 524288;

    #pragma unroll
    for (int mi = 0; mi < 4; mi++) {
        #pragma unroll
        for (int ni = 0; ni < 4; ni++) {
            f32x4 v = acc[mi][ni];
            const int m0 = mb + mi * 16 + quad * 4;       // global row
            const int n  = nb + ni * 16 + l16;
            float o[4];
            #pragma unroll
            for (int r = 0; r < 4; r++) o[r] = v[r] + bqkv[m0 + r];
            const int ml = m0 & 511;                      // row within matrix
            if (mat == 2) {
                #pragma unroll
                for (int r = 0; r < 4; r++)
                    vB[zb + (long)(ml + r) * 1024 + n] = f2bf(o[r]);
            } else {
                unsigned short* dst = (mat == 0) ? qT : kT;
                ushort4 p; p.x = f2bf(o[0]); p.y = f2bf(o[1]); p.z = f2bf(o[2]); p.w = f2bf(o[3]);
                *(ushort4*)(dst + zb + (long)n * 512 + ml) = p;
            }
        }
    }
}

// ==========================================================================
// GroupNorm: x[b][c][n] (fp32) -> xnT[b][n][c] (bf16), 32 groups of 16 ch
// ==========================================================================
__global__ __launch_bounds__(256) void gn_k(
    const float* __restrict__ x, const float* __restrict__ gsc,
    const float* __restrict__ gbi, unsigned short* __restrict__ xnT)
{
    __shared__ __align__(16) unsigned short ln[16 * 1024];
    __shared__ float red[8];
    const int b = blockIdx.y, g = blockIdx.x;
    const int tid = threadIdx.x, lane = tid & 63, wv = tid >> 6;

    const float4* x4 = (const float4*)(x + ((long)b * 512 + g * 16) * 1024);
    float4 vals[16];
    float s = 0.f, ss = 0.f;
    #pragma unroll
    for (int i = 0; i < 16; i++) {
        float4 v = x4[tid + i * 256];
        vals[i] = v;
        s  += v.x + v.y + v.z + v.w;
        ss += v.x * v.x + v.y * v.y + v.z * v.z + v.w * v.w;
    }
    for (int o = 32; o; o >>= 1) { s += __shfl_down(s, o); ss += __shfl_down(ss, o); }
    if (lane == 0) { red[wv * 2] = s; red[wv * 2 + 1] = ss; }
    __syncthreads();
    const float S  = red[0] + red[2] + red[4] + red[6];
    const float SS = red[1] + red[3] + red[5] + red[7];
    const float mean = S * (1.f / 16384.f);
    const float var  = SS * (1.f / 16384.f) - mean * mean;
    const float inv  = rsqrtf(var + 1e-5f);

    #pragma unroll
    for (int i = 0; i < 16; i++) {
        const int idx = tid + i * 256;
        const int c   = idx >> 8;
        const float sc = gsc[g * 16 + c] * inv;
        const float bi = gbi[g * 16 + c] - mean * sc;
        float4 v = vals[i];
        ushort4 p;
        p.x = f2bf(v.x * sc + bi); p.y = f2bf(v.y * sc + bi);
        p.z = f2bf(v.z * sc + bi); p.w = f2bf(v.w * sc + bi);
        ((ushort4*)ln)[idx] = p;
    }
    __syncthreads();

    unsigned short* op = xnT + (long)b * 1024 * 512 + g * 16;
    for (int rep = 0; rep < 4; rep++) {
        const int n = rep * 256 + tid;
        union { unsigned short u[16]; uint4 v[2]; } t;
        #pragma unroll
        for (int c = 0; c < 16; c++) t.u[c] = ln[c * 1024 + n];
        *(uint4*)&op[(long)n * 512]     = t.v[0];
        *(uint4*)&op[(long)n * 512 + 8] = t.v[1];
    }
}

// ---------- weights fp32 -> bf16 + bias concat + lsum zero (y==4 path) ----
__global__ __launch_bounds__(256) void wconv_k(
    const float* __restrict__ w0, const float* __restrict__ w1,
    const float* __restrict__ w2, const float* __restrict__ w3,
    const float* __restrict__ b0, const float* __restrict__ b1,
    const float* __restrict__ b2,
    unsigned short* __restrict__ out, float* __restrict__ bqkv,
    float* __restrict__ lsum)
{
    const int m = blockIdx.y;
    const int i = blockIdx.x * 256 + threadIdx.x;
    if (m == 4) {
        if (i < 384) {
            const int which = i >> 7, off = i & 127;
            const float* src = (which == 0) ? b0 : (which == 1) ? b1 : b2;
            ((float4*)bqkv)[i] = ((const float4*)src)[off];
        }
        if (i < 16384) lsum[i] = 0.f;   // zero [16][1024] row-sum buffer
        return;
    }
    const float* src = (m == 0) ? w0 : (m == 1) ? w1 : (m == 2) ? w2 : w3;
    float4 v = ((const float4*)src)[i];
    ushort4 o; o.x = f2bf(v.x); o.y = f2bf(v.y); o.z = f2bf(v.z); o.w = f2bf(v.w);
    ((ushort4*)(out + (long)m * 262144))[i] = o;
}

// ==========================================================================
extern "C" void kernel_launch(void* const* d_in, const int* in_sizes, int n_in,
                              void* d_out, int out_size, void* d_ws, size_t ws_size,
                              hipStream_t stream)
{
    const float* x   = (const float*)d_in[0];
    const float* gsc = (const float*)d_in[1];
    const float* gbi = (const float*)d_in[2];
    const float* wq  = (const float*)d_in[3];
    const float* bq  = (const float*)d_in[4];
    const float* wk  = (const float*)d_in[5];
    const float* bk  = (const float*)d_in[6];
    const float* wv  = (const float*)d_in[7];
    const float* bv  = (const float*)d_in[8];
    const float* wp  = (const float*)d_in[9];
    const float* bp  = (const float*)d_in[10];
    float* out = (float*)d_out;

    char* ws = (char*)d_ws;
    unsigned short* xnT = (unsigned short*)(ws);               // 16 MB [b][n][c]; reused as OT
    unsigned short* qT  = (unsigned short*)(ws + 16777216);    // 16 MB [b][i][c]
    unsigned short* kT  = (unsigned short*)(ws + 33554432);    // 16 MB [b][j][c]
    unsigned short* vB  = (unsigned short*)(ws + 50331648);    // 16 MB [b][c][j]
    unsigned short* Sb  = (unsigned short*)(ws + 67108864);    // 32 MB [b][i][j] bf16 (P' = exp)
    unsigned short* Wb  = (unsigned short*)(ws + 100663296);   // 2 MB: wq|wk|wv|wp bf16
    float*          bqkv= (float*)        (ws + 102760448);    // 6 KB
    float*          Lb  = (float*)        (ws + 102768640);    // 64 KB [b][i] row sums
    unsigned short* OT  = xnT;

    const long sBCN = 512L * 1024;

    wconv_k<<<dim3(256, 5), 256, 0, stream>>>(wq, wk, wv, wp, bq, bk, bv, Wb, bqkv, Lb);
    gn_k<<<dim3(32, 16), 256, 0, stream>>>(x, gsc, gbi, xnT);

    // fused QKV: qT[i][c], kT[j][c], vB[c][j]
    qkv_k<<<dim3(8, 12, 16), 256, 0, stream>>>(Wb, xnT, qT, kT, vB, bqkv);

    // P'[i][j] = exp(q·k/sqrt(512)) -> bf16; Lb[b][i] += row sums (atomics)
    gemm_k<unsigned short, false, false, false, true, false>
        <<<dim3(8, 8, 16), 256, 0, stream>>>(
        qT, sBCN, 512, kT, sBCN, 512, Sb, 1048576L, 1024, nullptr, nullptr, 0,
        Lb, 1024, 0.044194173824159216f, 512);

    // O[c][i] = sum_j v[c][j]*P'[i][j], scaled by 1/Lb[i] -> OT[i][c]
    gemm_k<unsigned short, true, false, false, false, true>
        <<<dim3(8, 4, 16), 256, 0, stream>>>(
        vB, sBCN, 1024, Sb, 1048576L, 1024, OT, sBCN, 512,
        nullptr, nullptr, 0, Lb, 1024, 1.f, 1024);

    // out = Wp * O + bp + x
    gemm_k<float, false, true, true, false, false>
        <<<dim3(8, 4, 16), 256, 0, stream>>>(
        Wb + 786432, 0, 512, OT, sBCN, 512, out, sBCN, 1024, bp, x, sBCN,
        nullptr, 0, 1.f, 512);
}